// Round 2
// baseline (256.990 us; speedup 1.0000x reference)
//
#include <hip/hip_runtime.h>
#include <stdint.h>

#define NQ   2562
#define MPTS 16384

// ---------------------------------------------------------------------------
// Kernel 1: copy inputs [N,3] into output columns 0..2 of [N,15]
// ---------------------------------------------------------------------------
__global__ __launch_bounds__(256)
void passthrough_kernel(const float* __restrict__ inp, float* __restrict__ out) {
    int gid = blockIdx.x * 256 + threadIdx.x;
    if (gid < NQ * 3) {
        int n = gid / 3, c = gid - n * 3;
        out[n * 15 + c] = inp[gid];
    }
}

// ---------------------------------------------------------------------------
// Kernel 2: one wave (64 threads) handles 4 query-instances q = 4*w .. 4*w+3,
// q = pc*NQ + n. Top-16 for query r lives sorted (ascending packed key) in
// lane group r (lanes 16r..16r+15), one u64 per lane:
//   packed = (monotonic_u32(d2_key) << 32) | point_index
// so u64 ordering == (d2, idx) ordering (ties -> lower index, like top_k).
// ---------------------------------------------------------------------------
__global__ __launch_bounds__(64)
void knn_kernel(const float* __restrict__ inp,
                const float* __restrict__ pc0, const float* __restrict__ pc1,
                const float* __restrict__ pc2, const float* __restrict__ pc3,
                float* __restrict__ out) {
    const int w    = blockIdx.x;      // 0..2561
    const int lane = threadIdx.x;     // 0..63
    const int grp  = lane >> 4;       // which 16-lane group
    const int l16  = lane & 15;

    // Per-wave 4 queries: coefficients (uniform across lanes, live in VGPRs)
    float A2[4], B2[4], C2[4], XS[4];
    int   pcid[4];
    const float* Pr[4];
#pragma unroll
    for (int r = 0; r < 4; ++r) {
        int q  = 4 * w + r;
        int pc = q / NQ;              // magic-mul division
        int n  = q - pc * NQ;
        pcid[r] = pc;
        const float* P = (pc == 0) ? pc0 : (pc == 1) ? pc1 : (pc == 2) ? pc2 : pc3;
        Pr[r] = P;
        float x0 = inp[n * 3 + 0];
        float x1 = inp[n * 3 + 1];
        float x2 = inp[n * 3 + 2];
        A2[r] = 2.0f * x0;            // exact scaling
        B2[r] = 2.0f * x1;
        C2[r] = 2.0f * x2;
        // x^2 sum: numpy elementwise left-assoc, no fma
        XS[r] = __fadd_rn(__fadd_rn(__fmul_rn(x0, x0), __fmul_rn(x1, x1)),
                          __fmul_rn(x2, x2));
    }

    const bool uni = (pcid[0] == pcid[3]);   // all 4 queries share one pc
    const float* P0 = Pr[0];

    unsigned long long s = ~0ULL;            // my slot of my group's sorted-16
    unsigned long long kth0 = ~0ULL, kth1 = ~0ULL, kth2 = ~0ULL, kth3 = ~0ULL;

    for (int base = 0; base < MPTS; base += 64) {
        const int m = base + lane;
        float y0, y1, y2, ysq;
        if (uni) {
            y0 = P0[m]; y1 = P0[MPTS + m]; y2 = P0[2 * MPTS + m];
            ysq = __fadd_rn(__fadd_rn(__fmul_rn(y0, y0), __fmul_rn(y1, y1)),
                            __fmul_rn(y2, y2));
        }
#pragma unroll
        for (int r = 0; r < 4; ++r) {
            float z0 = y0, z1 = y1, z2 = y2, zsq = ysq;
            if (!uni) {   // rare boundary waves: per-query point stream
                const float* P = Pr[r];
                z0 = P[m]; z1 = P[MPTS + m]; z2 = P[2 * MPTS + m];
                zsq = __fadd_rn(__fadd_rn(__fmul_rn(z0, z0), __fmul_rn(z1, z1)),
                                __fmul_rn(z2, z2));
            }
            // 2*x.y as fma chain with pre-doubled coeffs (mirrors sgemm k-loop)
            float u = fmaf(C2[r], z2, fmaf(B2[r], z1, __fmul_rn(A2[r], z0)));
            float key = __fsub_rn(__fadd_rn(XS[r], zsq), u);
            uint32_t kb = __float_as_uint(key);
            kb ^= (uint32_t)((int32_t)kb >> 31) | 0x80000000u;  // total order map
            unsigned long long pk =
                ((unsigned long long)kb << 32) | (unsigned)m;

            unsigned long long kth = (r == 0) ? kth0 : (r == 1) ? kth1
                                   : (r == 2) ? kth2 : kth3;
            unsigned long long ball = __ballot(pk < kth);
            while (ball) {
                int src = __ffsll(ball) - 1;
                ball &= ball - 1;
                unsigned long long cand = __shfl(pk, src);
                // distributed sorted insert (inserting cand >= current max is a no-op)
                unsigned long long sp = __shfl_up(s, 1, 16);
                unsigned long long ns;
                if (s < cand)                      ns = s;      // stays
                else if (l16 == 0 || sp < cand)    ns = cand;   // insert here
                else                               ns = sp;     // shifted up
                if (grp == r) s = ns;
                kth = __shfl(s, r * 16 + 15);
            }
            if (r == 0) kth0 = kth; else if (r == 1) kth1 = kth;
            else if (r == 2) kth2 = kth; else kth3 = kth;
        }
    }

    // Gather the 16 winners' coordinates and mean them (per 16-lane group)
    {
        int qg  = 4 * w + grp;
        int pcg = qg / NQ;
        int ng  = qg - pcg * NQ;
        const float* Pg = (pcg == 0) ? pc0 : (pcg == 1) ? pc1
                        : (pcg == 2) ? pc2 : pc3;
        int idx = (int)(unsigned)s;       // low 32 bits = point index
        float gx = Pg[idx];
        float gy = Pg[MPTS + idx];
        float gz = Pg[2 * MPTS + idx];
#pragma unroll
        for (int off = 8; off > 0; off >>= 1) {
            gx += __shfl_down(gx, off, 16);
            gy += __shfl_down(gy, off, 16);
            gz += __shfl_down(gz, off, 16);
        }
        if (l16 == 0) {
            float* o = out + ng * 15 + 3 + 3 * pcg;
            o[0] = gx * 0.0625f;
            o[1] = gy * 0.0625f;
            o[2] = gz * 0.0625f;
        }
    }
}

extern "C" void kernel_launch(void* const* d_in, const int* in_sizes, int n_in,
                              void* d_out, int out_size, void* d_ws, size_t ws_size,
                              hipStream_t stream) {
    const float* inp = (const float*)d_in[0];
    const float* pc0 = (const float*)d_in[1];
    const float* pc1 = (const float*)d_in[2];
    const float* pc2 = (const float*)d_in[3];
    const float* pc3 = (const float*)d_in[4];
    float* out = (float*)d_out;

    hipLaunchKernelGGL(passthrough_kernel, dim3((NQ * 3 + 255) / 256), dim3(256),
                       0, stream, inp, out);

    // 4 pcs * 2562 queries = 10248 query-instances, 4 per wave -> 2562 waves
    hipLaunchKernelGGL(knn_kernel, dim3(2562), dim3(64), 0, stream,
                       inp, pc0, pc1, pc2, pc3, out);
}